// Round 4
// baseline (479.544 us; speedup 1.0000x reference)
//
#include <hip/hip_runtime.h>

#define NN 50000
#define EE 800000
#define NB 30
#define NJ 1152   // 8 relations * 128 + 128 loop cols
#define NSB 49    // scan blocks: 49*1024 = 50176 nodes covered
#define NPART 16
#define RANGE 3136     // NPART*RANGE = 50176 >= NN
#define NSLICE 8
#define ESL 100000     // EE / NSLICE
#define NPAD 50176

typedef __attribute__((ext_vector_type(8))) short short8;
typedef __attribute__((ext_vector_type(4))) float f32x4;

__device__ __forceinline__ unsigned short f2bf(float f) {
  unsigned u = __float_as_uint(f);
  u += 0x7FFF + ((u >> 16) & 1);           // round-to-nearest-even
  return (unsigned short)(u >> 16);
}
__device__ __forceinline__ float bf2f(unsigned short s) {
  return __uint_as_float(((unsigned)s) << 16);
}

// ---- build Wt[j][k] (bf16, j = r*128+o for r<8, j>=1024 -> loop_weight), W2t[o][k] ----
__global__ void k_prep(const float* __restrict__ wcomp, const float* __restrict__ bases,
                       const float* __restrict__ loopw, const float* __restrict__ W2,
                       unsigned short* __restrict__ Wt, unsigned short* __restrict__ W2t) {
  int idx = blockIdx.x * 256 + threadIdx.x;
  if (idx < NJ * 128) {
    int j = idx >> 7, k = idx & 127;
    float v;
    if (j < 1024) {
      int r = j >> 7, o = j & 127;
      float s = 0.f;
#pragma unroll
      for (int b = 0; b < NB; ++b)
        s = fmaf(wcomp[r * NB + b], bases[((size_t)b * 128 + k) * 128 + o], s);
      v = s;
    } else {
      v = loopw[k * 128 + (j - 1024)];
    }
    Wt[idx] = f2bf(v);
  }
  if (idx < 128 * 128) {
    int j = idx >> 7, k = idx & 127;
    W2t[idx] = f2bf(W2[k * 128 + j]);
  }
}

// ---- X (f32) -> bf16 ----
__global__ void k_xbf(const float* __restrict__ X, unsigned short* __restrict__ Xbf) {
  int i = (blockIdx.x * 256 + threadIdx.x) * 4;
  float4 v = *(const float4*)(X + i);
  uint2 o;
  o.x = (unsigned)f2bf(v.x) | ((unsigned)f2bf(v.y) << 16);
  o.y = (unsigned)f2bf(v.z) | ((unsigned)f2bf(v.w) << 16);
  *(uint2*)(Xbf + i) = o;
}

// ---- partitioned LDS degree histograms (no global atomics) ----
// 256 blocks: bit0 = kind (0: din from dst, 1: dout from src), bits1-3 = slice, bits4+ = partition
__global__ __launch_bounds__(256) void k_hist(const int* __restrict__ EI,
                                              int* __restrict__ pdin, int* __restrict__ pdout) {
  __shared__ int hist[RANGE];
  int b = blockIdx.x;
  int kind = b & 1;
  int sl = (b >> 1) & 7;
  int r = b >> 4;
  const int base = r * RANGE;
  const int* vals = kind ? EI : EI + EE;   // kind1: src, kind0: dst
  int* part = kind ? pdout : pdin;
  for (int j = threadIdx.x; j < RANGE; j += 256) hist[j] = 0;
  __syncthreads();
  const int e0 = sl * ESL;
  for (int i = threadIdx.x; i < ESL / 4; i += 256) {
    int4 d = *(const int4*)(vals + e0 + i * 4);
    int x;
    x = d.x - base; if ((unsigned)x < RANGE) atomicAdd(&hist[x], 1);
    x = d.y - base; if ((unsigned)x < RANGE) atomicAdd(&hist[x], 1);
    x = d.z - base; if ((unsigned)x < RANGE) atomicAdd(&hist[x], 1);
    x = d.w - base; if ((unsigned)x < RANGE) atomicAdd(&hist[x], 1);
  }
  __syncthreads();
  for (int j = threadIdx.x; j < RANGE; j += 256)
    part[sl * NPAD + base + j] = hist[j];
}

// ---- A) reduce partials (din & dout) + per-block sums of din ----
__global__ __launch_bounds__(256) void k_scan_a(const int* __restrict__ pdin,
                                                const int* __restrict__ pdout,
                                                int* __restrict__ din,
                                                int* __restrict__ dout,
                                                int* __restrict__ bsum) {
  __shared__ int wsum[4];
  int b = blockIdx.x, t = threadIdx.x;
  int lane = t & 63, w = t >> 6;
  int i0 = b * 1024 + t * 4;
  int4 acc = {0, 0, 0, 0}, od = {0, 0, 0, 0};
#pragma unroll
  for (int sl = 0; sl < NSLICE; ++sl) {
    int4 a = *(const int4*)(pdin + sl * NPAD + i0);
    int4 o = *(const int4*)(pdout + sl * NPAD + i0);
    acc.x += a.x; acc.y += a.y; acc.z += a.z; acc.w += a.w;
    od.x += o.x; od.y += o.y; od.z += o.z; od.w += o.w;
  }
  *(int4*)(din + i0) = acc;
  *(int4*)(dout + i0) = od;
  int sv = acc.x + acc.y + acc.z + acc.w;
#pragma unroll
  for (int off = 32; off; off >>= 1) sv += __shfl_down(sv, off, 64);
  if (lane == 0) wsum[w] = sv;
  __syncthreads();
  if (t == 0) bsum[b] = wsum[0] + wsum[1] + wsum[2] + wsum[3];
}

// ---- B) exclusive scan of the 49 block sums (one wave) ----
__global__ void k_scan_b(int* __restrict__ bsum, int* __restrict__ row_ptr) {
  int t = threadIdx.x;  // 64 threads
  int v = (t < NSB) ? bsum[t] : 0;
  int orig = v;
#pragma unroll
  for (int off = 1; off < 64; off <<= 1) {
    int u = __shfl_up(v, off, 64);
    if (t >= off) v += u;
  }
  if (t < NSB) bsum[t] = v - orig;   // exclusive block offset
  if (t == 0) row_ptr[NN] = EE;
}

// ---- C) block-level exclusive scan + offset -> row_ptr ----
__global__ __launch_bounds__(256) void k_scan_c(const int* __restrict__ din,
                                                const int* __restrict__ bsum,
                                                int* __restrict__ row_ptr) {
  __shared__ int wsum[4];
  int b = blockIdx.x, t = threadIdx.x;
  int lane = t & 63, w = t >> 6;
  int i0 = b * 1024 + t * 4;
  int4 d = *(const int4*)(din + i0);
  int sth = d.x + d.y + d.z + d.w;
  int v = sth;
#pragma unroll
  for (int off = 1; off < 64; off <<= 1) {
    int u = __shfl_up(v, off, 64);
    if (lane >= off) v += u;
  }
  if (lane == 63) wsum[w] = v;
  __syncthreads();
  int woff = 0;
  for (int j = 0; j < w; ++j) woff += wsum[j];
  int base = bsum[b] + woff + (v - sth);
  row_ptr[i0 + 0] = base; base += d.x;
  row_ptr[i0 + 1] = base; base += d.y;
  row_ptr[i0 + 2] = base; base += d.z;
  row_ptr[i0 + 3] = base;
}

// ---- scatter packed edge metadata into dst-CSR order via LDS cursors ----
// 128 blocks: bits0-2 = slice, bits3+ = partition
__global__ __launch_bounds__(256) void k_scatter(const int* __restrict__ src,
                                                 const int* __restrict__ dst,
                                                 const int* __restrict__ ety,
                                                 const float* __restrict__ enorm,
                                                 const int* __restrict__ pdin,
                                                 const int* __restrict__ row_ptr,
                                                 int2* __restrict__ em1,
                                                 int2* __restrict__ em2) {
  __shared__ int cur[RANGE];
  int b = blockIdx.x;
  int sl = b & 7, r = b >> 3;
  const int base = r * RANGE;
  for (int j = threadIdx.x; j < RANGE; j += 256) {
    int off = row_ptr[base + j];
    for (int sp = 0; sp < sl; ++sp) off += pdin[sp * NPAD + base + j];
    cur[j] = off;
  }
  __syncthreads();
  const int e0 = sl * ESL;
  for (int i = threadIdx.x; i < ESL / 4; i += 256) {
    int4 d = *(const int4*)(dst + e0 + i * 4);
    int vals[4] = {d.x, d.y, d.z, d.w};
#pragma unroll
    for (int j = 0; j < 4; ++j) {
      int dv = vals[j] - base;
      if ((unsigned)dv < RANGE) {
        int e = e0 + i * 4 + j;
        int pos = atomicAdd(&cur[dv], 1);     // LDS fetch-add
        int sv = src[e];
        int wb = __float_as_int(enorm[e]);
        em1[pos] = make_int2(sv * NJ + ety[e] * 128, wb);
        em2[pos] = make_int2(sv * 128, wb);
      }
    }
  }
}

// ---- bf16 MFMA GEMM: C[M][ldc] = A[M][128] * B^T (B given as [Ncols][128]) ----
__global__ __launch_bounds__(256) void k_gemm(const unsigned short* __restrict__ A,
                                              const unsigned short* __restrict__ B,
                                              unsigned short* __restrict__ Cbf,
                                              float* __restrict__ Cf,
                                              const float* __restrict__ bias,
                                              int M, int ldc) {
  __shared__ unsigned short As[128 * 136];   // row stride 272 B
  __shared__ unsigned short Bs[128 * 136];
  const int m0 = blockIdx.x * 128, j0 = blockIdx.y * 128;
  const int t = threadIdx.x;
  for (int i = t; i < 2048; i += 256) {
    int r = i >> 4, c = i & 15;
    uint4 va = {0, 0, 0, 0};
    int gr = m0 + r;
    if (gr < M) va = *(const uint4*)(A + (size_t)gr * 128 + c * 8);
    *(uint4*)(&As[r * 136 + c * 8]) = va;
    uint4 vb = *(const uint4*)(B + (size_t)(j0 + r) * 128 + c * 8);
    *(uint4*)(&Bs[r * 136 + c * 8]) = vb;
  }
  __syncthreads();

  const int lane = t & 63, wave = t >> 6;
  const int wr = (wave >> 1) * 64, wc = (wave & 1) * 64;
  const int lr = lane & 15, lk = (lane >> 4) * 8;

  f32x4 acc[4][4];
#pragma unroll
  for (int m = 0; m < 4; ++m)
#pragma unroll
    for (int n = 0; n < 4; ++n) acc[m][n] = (f32x4){0.f, 0.f, 0.f, 0.f};

#pragma unroll
  for (int kt = 0; kt < 4; ++kt) {
    short8 af[4], bfr[4];
#pragma unroll
    for (int m = 0; m < 4; ++m)
      af[m] = *(const short8*)(&As[(wr + m * 16 + lr) * 136 + kt * 32 + lk]);
#pragma unroll
    for (int n = 0; n < 4; ++n)
      bfr[n] = *(const short8*)(&Bs[(wc + n * 16 + lr) * 136 + kt * 32 + lk]);
#pragma unroll
    for (int m = 0; m < 4; ++m)
#pragma unroll
      for (int n = 0; n < 4; ++n)
        acc[m][n] = __builtin_amdgcn_mfma_f32_16x16x32_bf16(af[m], bfr[n], acc[m][n], 0, 0, 0);
  }

#pragma unroll
  for (int m = 0; m < 4; ++m) {
    int rbase = m0 + wr + m * 16 + (lane >> 4) * 4;
#pragma unroll
    for (int i = 0; i < 4; ++i) {
      int row = rbase + i;
      if (row >= M) continue;
      if (Cbf) {
        unsigned short* cr = Cbf + (size_t)row * ldc + j0 + wc;
#pragma unroll
        for (int n = 0; n < 4; ++n) cr[n * 16 + lr] = f2bf(acc[m][n][i]);
      } else {
        float* cr = Cf + (size_t)row * ldc + j0 + wc;
#pragma unroll
        for (int n = 0; n < 4; ++n) cr[n * 16 + lr] = acc[m][n][i] + bias[j0 + wc + n * 16 + lr];
      }
    }
  }
}

#define UNR 8

// ---- layer-1 aggregation: wave per dst node, 8-wide ILP unroll ----
__global__ __launch_bounds__(256) void k_agg1(const unsigned short* __restrict__ xw,
                                              const int2* __restrict__ em1,
                                              const int* __restrict__ row_ptr,
                                              const int* __restrict__ deg_out,
                                              const float* __restrict__ bias1,
                                              unsigned short* __restrict__ hs) {
  int gw = (blockIdx.x * blockDim.x + threadIdx.x) >> 6;
  int lane = threadIdx.x & 63;
  if (gw >= NN) return;
  int beg = row_ptr[gw], end = row_ptr[gw + 1];
  float a0 = 0.f, a1 = 0.f;
  for (int i = beg; i < end; i += UNR) {
    int2 md[UNR];
    unsigned v[UNR];
#pragma unroll
    for (int j = 0; j < UNR; ++j) {
      int idx = i + j;
      idx = idx < end ? idx : end - 1;          // pad: duplicate last edge (MSHR-merged)
      md[j] = em1[idx];
      if (i + j >= end) md[j].y = 0;            // pad weight = 0
    }
#pragma unroll
    for (int j = 0; j < UNR; ++j)
      v[j] = *(const unsigned*)(xw + (size_t)(unsigned)md[j].x + lane * 2);
#pragma unroll
    for (int j = 0; j < UNR; ++j) {
      float w = __int_as_float(md[j].y);
      a0 = fmaf(w, bf2f((unsigned short)(v[j] & 0xffff)), a0);
      a1 = fmaf(w, bf2f((unsigned short)(v[j] >> 16)), a1);
    }
  }
  unsigned vl = *(const unsigned*)(xw + (size_t)gw * NJ + 1024 + lane * 2);
  float ns = rsqrtf(fmaxf((float)deg_out[gw], 1.f));
  float h0 = (a0 + bf2f((unsigned short)(vl & 0xffff)) + bias1[lane * 2]) * ns;
  float h1 = (a1 + bf2f((unsigned short)(vl >> 16)) + bias1[lane * 2 + 1]) * ns;
  unsigned o = (unsigned)f2bf(h0) | ((unsigned)f2bf(h1) << 16);
  *(unsigned*)(hs + (size_t)gw * 128 + lane * 2) = o;
}

// ---- layer-2 aggregation: same structure over hs ----
__global__ __launch_bounds__(256) void k_agg2(const unsigned short* __restrict__ hs,
                                              const int2* __restrict__ em2,
                                              const int* __restrict__ row_ptr,
                                              unsigned short* __restrict__ zb) {
  int gw = (blockIdx.x * blockDim.x + threadIdx.x) >> 6;
  int lane = threadIdx.x & 63;
  if (gw >= NN) return;
  int beg = row_ptr[gw], end = row_ptr[gw + 1];
  float a0 = 0.f, a1 = 0.f;
  for (int i = beg; i < end; i += UNR) {
    int2 md[UNR];
    unsigned v[UNR];
#pragma unroll
    for (int j = 0; j < UNR; ++j) {
      int idx = i + j;
      idx = idx < end ? idx : end - 1;
      md[j] = em2[idx];
      if (i + j >= end) md[j].y = 0;
    }
#pragma unroll
    for (int j = 0; j < UNR; ++j)
      v[j] = *(const unsigned*)(hs + (size_t)(unsigned)md[j].x + lane * 2);
#pragma unroll
    for (int j = 0; j < UNR; ++j) {
      float w = __int_as_float(md[j].y);
      a0 = fmaf(w, bf2f((unsigned short)(v[j] & 0xffff)), a0);
      a1 = fmaf(w, bf2f((unsigned short)(v[j] >> 16)), a1);
    }
  }
  float nd = rsqrtf(fmaxf((float)(end - beg), 1.f));
  unsigned o = (unsigned)f2bf(a0 * nd) | ((unsigned)f2bf(a1 * nd) << 16);
  *(unsigned*)(zb + (size_t)gw * 128 + lane * 2) = o;
}

extern "C" void kernel_launch(void* const* d_in, const int* in_sizes, int n_in,
                              void* d_out, int out_size, void* d_ws, size_t ws_size,
                              hipStream_t stream) {
  const float* X = (const float*)d_in[0];
  const int* EI = (const int*)d_in[1];
  const float* enorm = (const float*)d_in[2];
  const int* etype = (const int*)d_in[3];
  const float* wcomp = (const float*)d_in[4];
  const float* bases = (const float*)d_in[5];
  const float* loopw = (const float*)d_in[6];
  const float* bias1 = (const float*)d_in[7];
  const float* W2 = (const float*)d_in[8];
  const float* bias2 = (const float*)d_in[9];
  float* out = (float*)d_out;
  const int* srcA = EI;
  const int* dstA = EI + EE;

  char* p = (char*)d_ws;
  auto alloc = [&](size_t bytes) {
    char* r = p;
    p += (bytes + 255) & ~(size_t)255;
    return r;
  };
  unsigned short* xw  = (unsigned short*)alloc((size_t)NN * NJ * 2);  // 115.2 MB
  unsigned short* Xbf = (unsigned short*)alloc((size_t)NN * 128 * 2);
  unsigned short* hs  = (unsigned short*)alloc((size_t)NN * 128 * 2);
  unsigned short* zb  = (unsigned short*)alloc((size_t)NN * 128 * 2);
  unsigned short* Wt  = (unsigned short*)alloc((size_t)NJ * 128 * 2);
  unsigned short* W2t = (unsigned short*)alloc(128 * 128 * 2);
  int* pdin    = (int*)alloc((size_t)NSLICE * NPAD * 4);
  int* pdout   = (int*)alloc((size_t)NSLICE * NPAD * 4);
  int* din     = (int*)alloc((size_t)NPAD * 4);
  int* dout    = (int*)alloc((size_t)NPAD * 4);
  int* row_ptr = (int*)alloc((size_t)(NPAD + 1) * 4);
  int* bsum    = (int*)alloc((size_t)NSB * 4);
  int2* em1    = (int2*)alloc((size_t)EE * 8);
  int2* em2    = (int2*)alloc((size_t)EE * 8);

  hipLaunchKernelGGL(k_prep, dim3(576), dim3(256), 0, stream, wcomp, bases, loopw, W2, Wt, W2t);
  hipLaunchKernelGGL(k_xbf, dim3(6250), dim3(256), 0, stream, X, Xbf);
  hipLaunchKernelGGL(k_hist, dim3(256), dim3(256), 0, stream, EI, pdin, pdout);
  hipLaunchKernelGGL(k_scan_a, dim3(NSB), dim3(256), 0, stream, pdin, pdout, din, dout, bsum);
  hipLaunchKernelGGL(k_scan_b, dim3(1), dim3(64), 0, stream, bsum, row_ptr);
  hipLaunchKernelGGL(k_scan_c, dim3(NSB), dim3(256), 0, stream, din, bsum, row_ptr);
  hipLaunchKernelGGL(k_scatter, dim3(128), dim3(256), 0, stream,
                     srcA, dstA, etype, enorm, pdin, row_ptr, em1, em2);
  hipLaunchKernelGGL(k_gemm, dim3(391, 9), dim3(256), 0, stream,
                     Xbf, Wt, xw, (float*)nullptr, (const float*)nullptr, NN, NJ);
  hipLaunchKernelGGL(k_agg1, dim3(12500), dim3(256), 0, stream,
                     xw, em1, row_ptr, dout, bias1, hs);
  hipLaunchKernelGGL(k_agg2, dim3(12500), dim3(256), 0, stream,
                     hs, em2, row_ptr, zb);
  hipLaunchKernelGGL(k_gemm, dim3(391, 1), dim3(256), 0, stream,
                     zb, W2t, (unsigned short*)nullptr, out, bias2, NN, 128);
}

// Round 5
// 364.277 us; speedup vs baseline: 1.3164x; 1.3164x over previous
//
#include <hip/hip_runtime.h>

#define NN 50000
#define EE 800000
#define NB 30
#define NJ 1152   // 8 relations * 128 + 128 loop cols
#define NSB 49    // scan blocks: 49*1024 = 50176 nodes covered
#define NPART 16
#define RANGE 3136     // NPART*RANGE = 50176 >= NN
#define NSLICE 8
#define ESL 100000     // EE / NSLICE
#define NPAD 50176

typedef __attribute__((ext_vector_type(8))) short short8;
typedef __attribute__((ext_vector_type(4))) float f32x4;

__device__ __forceinline__ unsigned short f2bf(float f) {
  unsigned u = __float_as_uint(f);
  u += 0x7FFF + ((u >> 16) & 1);           // round-to-nearest-even
  return (unsigned short)(u >> 16);
}
__device__ __forceinline__ float bf2f(unsigned short s) {
  return __uint_as_float(((unsigned)s) << 16);
}

// ---- build Wt[j][k] (bf16, j = r*128+o for r<8, j>=1024 -> loop_weight), W2t[o][k] ----
__global__ void k_prep(const float* __restrict__ wcomp, const float* __restrict__ bases,
                       const float* __restrict__ loopw, const float* __restrict__ W2,
                       unsigned short* __restrict__ Wt, unsigned short* __restrict__ W2t) {
  int idx = blockIdx.x * 256 + threadIdx.x;
  if (idx < NJ * 128) {
    int j = idx >> 7, k = idx & 127;
    float v;
    if (j < 1024) {
      int r = j >> 7, o = j & 127;
      float s = 0.f;
#pragma unroll
      for (int b = 0; b < NB; ++b)
        s = fmaf(wcomp[r * NB + b], bases[((size_t)b * 128 + k) * 128 + o], s);
      v = s;
    } else {
      v = loopw[k * 128 + (j - 1024)];
    }
    Wt[idx] = f2bf(v);
  }
  if (idx < 128 * 128) {
    int j = idx >> 7, k = idx & 127;
    W2t[idx] = f2bf(W2[k * 128 + j]);
  }
}

// ---- X (f32) -> bf16 ----
__global__ void k_xbf(const float* __restrict__ X, unsigned short* __restrict__ Xbf) {
  int i = (blockIdx.x * 256 + threadIdx.x) * 4;
  float4 v = *(const float4*)(X + i);
  uint2 o;
  o.x = (unsigned)f2bf(v.x) | ((unsigned)f2bf(v.y) << 16);
  o.y = (unsigned)f2bf(v.z) | ((unsigned)f2bf(v.w) << 16);
  *(uint2*)(Xbf + i) = o;
}

// ---- partitioned LDS degree histograms (no global atomics) ----
// 256 blocks: bit0 = kind (0: din from dst, 1: dout from src), bits1-3 = slice, bits4+ = partition
__global__ __launch_bounds__(256) void k_hist(const int* __restrict__ EI,
                                              int* __restrict__ pdin, int* __restrict__ pdout) {
  __shared__ int hist[RANGE];
  int b = blockIdx.x;
  int kind = b & 1;
  int sl = (b >> 1) & 7;
  int r = b >> 4;
  const int base = r * RANGE;
  const int* vals = kind ? EI : EI + EE;   // kind1: src, kind0: dst
  int* part = kind ? pdout : pdin;
  for (int j = threadIdx.x; j < RANGE; j += 256) hist[j] = 0;
  __syncthreads();
  const int e0 = sl * ESL;
  for (int i = threadIdx.x; i < ESL / 4; i += 256) {
    int4 d = *(const int4*)(vals + e0 + i * 4);
    int x;
    x = d.x - base; if ((unsigned)x < RANGE) atomicAdd(&hist[x], 1);
    x = d.y - base; if ((unsigned)x < RANGE) atomicAdd(&hist[x], 1);
    x = d.z - base; if ((unsigned)x < RANGE) atomicAdd(&hist[x], 1);
    x = d.w - base; if ((unsigned)x < RANGE) atomicAdd(&hist[x], 1);
  }
  __syncthreads();
  for (int j = threadIdx.x; j < RANGE; j += 256)
    part[sl * NPAD + base + j] = hist[j];
}

// ---- A) reduce partials (din & dout) + per-block sums of din ----
__global__ __launch_bounds__(256) void k_scan_a(const int* __restrict__ pdin,
                                                const int* __restrict__ pdout,
                                                int* __restrict__ din,
                                                int* __restrict__ dout,
                                                int* __restrict__ bsum) {
  __shared__ int wsum[4];
  int b = blockIdx.x, t = threadIdx.x;
  int lane = t & 63, w = t >> 6;
  int i0 = b * 1024 + t * 4;
  int4 acc = {0, 0, 0, 0}, od = {0, 0, 0, 0};
#pragma unroll
  for (int sl = 0; sl < NSLICE; ++sl) {
    int4 a = *(const int4*)(pdin + sl * NPAD + i0);
    int4 o = *(const int4*)(pdout + sl * NPAD + i0);
    acc.x += a.x; acc.y += a.y; acc.z += a.z; acc.w += a.w;
    od.x += o.x; od.y += o.y; od.z += o.z; od.w += o.w;
  }
  *(int4*)(din + i0) = acc;
  *(int4*)(dout + i0) = od;
  int sv = acc.x + acc.y + acc.z + acc.w;
#pragma unroll
  for (int off = 32; off; off >>= 1) sv += __shfl_down(sv, off, 64);
  if (lane == 0) wsum[w] = sv;
  __syncthreads();
  if (t == 0) bsum[b] = wsum[0] + wsum[1] + wsum[2] + wsum[3];
}

// ---- B) exclusive scan of the 49 block sums (one wave) ----
__global__ void k_scan_b(int* __restrict__ bsum, int* __restrict__ row_ptr) {
  int t = threadIdx.x;  // 64 threads
  int v = (t < NSB) ? bsum[t] : 0;
  int orig = v;
#pragma unroll
  for (int off = 1; off < 64; off <<= 1) {
    int u = __shfl_up(v, off, 64);
    if (t >= off) v += u;
  }
  if (t < NSB) bsum[t] = v - orig;   // exclusive block offset
  if (t == 0) row_ptr[NN] = EE;
}

// ---- C) block-level exclusive scan + offset -> row_ptr, cursor ----
__global__ __launch_bounds__(256) void k_scan_c(const int* __restrict__ din,
                                                const int* __restrict__ bsum,
                                                int* __restrict__ row_ptr,
                                                int* __restrict__ cursor) {
  __shared__ int wsum[4];
  int b = blockIdx.x, t = threadIdx.x;
  int lane = t & 63, w = t >> 6;
  int i0 = b * 1024 + t * 4;
  int4 d = *(const int4*)(din + i0);
  int sth = d.x + d.y + d.z + d.w;
  int v = sth;
#pragma unroll
  for (int off = 1; off < 64; off <<= 1) {
    int u = __shfl_up(v, off, 64);
    if (lane >= off) v += u;
  }
  if (lane == 63) wsum[w] = v;
  __syncthreads();
  int woff = 0;
  for (int j = 0; j < w; ++j) woff += wsum[j];
  int base = bsum[b] + woff + (v - sth);
  if (i0 + 0 <= NN) { row_ptr[i0 + 0] = base; if (i0 + 0 < NN) cursor[i0 + 0] = base; } base += d.x;
  if (i0 + 1 <= NN) { row_ptr[i0 + 1] = base; if (i0 + 1 < NN) cursor[i0 + 1] = base; } base += d.y;
  if (i0 + 2 <= NN) { row_ptr[i0 + 2] = base; if (i0 + 2 < NN) cursor[i0 + 2] = base; } base += d.z;
  if (i0 + 3 <= NN) { row_ptr[i0 + 3] = base; if (i0 + 3 < NN) cursor[i0 + 3] = base; }
}

// ---- scatter packed edge metadata into dst-CSR order (global atomic cursor) ----
// em1 = {src*NJ + ety*128, enorm bits}   (for layer-1 gather from xw)
// em2 = {src*128,          enorm bits}   (for layer-2 gather from hs)
__global__ void k_csr(const int* __restrict__ src, const int* __restrict__ dst,
                      const int* __restrict__ ety, const float* __restrict__ enorm,
                      int* __restrict__ cursor,
                      int2* __restrict__ em1, int2* __restrict__ em2) {
  int e = blockIdx.x * 256 + threadIdx.x;
  if (e < EE) {
    int pos = atomicAdd(&cursor[dst[e]], 1);
    int s = src[e];
    int wb = __float_as_int(enorm[e]);
    em1[pos] = make_int2(s * NJ + ety[e] * 128, wb);
    em2[pos] = make_int2(s * 128, wb);
  }
}

// ---- bf16 MFMA GEMM: C[M][ldc] = A[M][128] * B^T (B given as [Ncols][128]) ----
__global__ __launch_bounds__(256) void k_gemm(const unsigned short* __restrict__ A,
                                              const unsigned short* __restrict__ B,
                                              unsigned short* __restrict__ Cbf,
                                              float* __restrict__ Cf,
                                              const float* __restrict__ bias,
                                              int M, int ldc) {
  __shared__ unsigned short As[128 * 136];   // row stride 272 B
  __shared__ unsigned short Bs[128 * 136];
  const int m0 = blockIdx.x * 128, j0 = blockIdx.y * 128;
  const int t = threadIdx.x;
  for (int i = t; i < 2048; i += 256) {
    int r = i >> 4, c = i & 15;
    uint4 va = {0, 0, 0, 0};
    int gr = m0 + r;
    if (gr < M) va = *(const uint4*)(A + (size_t)gr * 128 + c * 8);
    *(uint4*)(&As[r * 136 + c * 8]) = va;
    uint4 vb = *(const uint4*)(B + (size_t)(j0 + r) * 128 + c * 8);
    *(uint4*)(&Bs[r * 136 + c * 8]) = vb;
  }
  __syncthreads();

  const int lane = t & 63, wave = t >> 6;
  const int wr = (wave >> 1) * 64, wc = (wave & 1) * 64;
  const int lr = lane & 15, lk = (lane >> 4) * 8;

  f32x4 acc[4][4];
#pragma unroll
  for (int m = 0; m < 4; ++m)
#pragma unroll
    for (int n = 0; n < 4; ++n) acc[m][n] = (f32x4){0.f, 0.f, 0.f, 0.f};

#pragma unroll
  for (int kt = 0; kt < 4; ++kt) {
    short8 af[4], bfr[4];
#pragma unroll
    for (int m = 0; m < 4; ++m)
      af[m] = *(const short8*)(&As[(wr + m * 16 + lr) * 136 + kt * 32 + lk]);
#pragma unroll
    for (int n = 0; n < 4; ++n)
      bfr[n] = *(const short8*)(&Bs[(wc + n * 16 + lr) * 136 + kt * 32 + lk]);
#pragma unroll
    for (int m = 0; m < 4; ++m)
#pragma unroll
      for (int n = 0; n < 4; ++n)
        acc[m][n] = __builtin_amdgcn_mfma_f32_16x16x32_bf16(af[m], bfr[n], acc[m][n], 0, 0, 0);
  }

#pragma unroll
  for (int m = 0; m < 4; ++m) {
    int rbase = m0 + wr + m * 16 + (lane >> 4) * 4;
#pragma unroll
    for (int i = 0; i < 4; ++i) {
      int row = rbase + i;
      if (row >= M) continue;
      if (Cbf) {
        unsigned short* cr = Cbf + (size_t)row * ldc + j0 + wc;
#pragma unroll
        for (int n = 0; n < 4; ++n) cr[n * 16 + lr] = f2bf(acc[m][n][i]);
      } else {
        float* cr = Cf + (size_t)row * ldc + j0 + wc;
#pragma unroll
        for (int n = 0; n < 4; ++n) cr[n * 16 + lr] = acc[m][n][i] + bias[j0 + wc + n * 16 + lr];
      }
    }
  }
}

#define UNR 8

// ---- layer-1 aggregation: wave per dst node, 8-wide ILP unroll ----
__global__ __launch_bounds__(256) void k_agg1(const unsigned short* __restrict__ xw,
                                              const int2* __restrict__ em1,
                                              const int* __restrict__ row_ptr,
                                              const int* __restrict__ deg_out,
                                              const float* __restrict__ bias1,
                                              unsigned short* __restrict__ hs) {
  int gw = (blockIdx.x * blockDim.x + threadIdx.x) >> 6;
  int lane = threadIdx.x & 63;
  if (gw >= NN) return;
  int beg = row_ptr[gw], end = row_ptr[gw + 1];
  float a0 = 0.f, a1 = 0.f;
  for (int i = beg; i < end; i += UNR) {
    int2 md[UNR];
    unsigned v[UNR];
#pragma unroll
    for (int j = 0; j < UNR; ++j) {
      int idx = i + j;
      idx = idx < end ? idx : end - 1;          // pad: duplicate last edge (MSHR-merged)
      md[j] = em1[idx];
      if (i + j >= end) md[j].y = 0;            // pad weight = 0
    }
#pragma unroll
    for (int j = 0; j < UNR; ++j)
      v[j] = *(const unsigned*)(xw + (size_t)(unsigned)md[j].x + lane * 2);
#pragma unroll
    for (int j = 0; j < UNR; ++j) {
      float w = __int_as_float(md[j].y);
      a0 = fmaf(w, bf2f((unsigned short)(v[j] & 0xffff)), a0);
      a1 = fmaf(w, bf2f((unsigned short)(v[j] >> 16)), a1);
    }
  }
  unsigned vl = *(const unsigned*)(xw + (size_t)gw * NJ + 1024 + lane * 2);
  float ns = rsqrtf(fmaxf((float)deg_out[gw], 1.f));
  float h0 = (a0 + bf2f((unsigned short)(vl & 0xffff)) + bias1[lane * 2]) * ns;
  float h1 = (a1 + bf2f((unsigned short)(vl >> 16)) + bias1[lane * 2 + 1]) * ns;
  unsigned o = (unsigned)f2bf(h0) | ((unsigned)f2bf(h1) << 16);
  *(unsigned*)(hs + (size_t)gw * 128 + lane * 2) = o;
}

// ---- layer-2 aggregation: same structure over hs ----
__global__ __launch_bounds__(256) void k_agg2(const unsigned short* __restrict__ hs,
                                              const int2* __restrict__ em2,
                                              const int* __restrict__ row_ptr,
                                              unsigned short* __restrict__ zb) {
  int gw = (blockIdx.x * blockDim.x + threadIdx.x) >> 6;
  int lane = threadIdx.x & 63;
  if (gw >= NN) return;
  int beg = row_ptr[gw], end = row_ptr[gw + 1];
  float a0 = 0.f, a1 = 0.f;
  for (int i = beg; i < end; i += UNR) {
    int2 md[UNR];
    unsigned v[UNR];
#pragma unroll
    for (int j = 0; j < UNR; ++j) {
      int idx = i + j;
      idx = idx < end ? idx : end - 1;
      md[j] = em2[idx];
      if (i + j >= end) md[j].y = 0;
    }
#pragma unroll
    for (int j = 0; j < UNR; ++j)
      v[j] = *(const unsigned*)(hs + (size_t)(unsigned)md[j].x + lane * 2);
#pragma unroll
    for (int j = 0; j < UNR; ++j) {
      float w = __int_as_float(md[j].y);
      a0 = fmaf(w, bf2f((unsigned short)(v[j] & 0xffff)), a0);
      a1 = fmaf(w, bf2f((unsigned short)(v[j] >> 16)), a1);
    }
  }
  float nd = rsqrtf(fmaxf((float)(end - beg), 1.f));
  unsigned o = (unsigned)f2bf(a0 * nd) | ((unsigned)f2bf(a1 * nd) << 16);
  *(unsigned*)(zb + (size_t)gw * 128 + lane * 2) = o;
}

extern "C" void kernel_launch(void* const* d_in, const int* in_sizes, int n_in,
                              void* d_out, int out_size, void* d_ws, size_t ws_size,
                              hipStream_t stream) {
  const float* X = (const float*)d_in[0];
  const int* EI = (const int*)d_in[1];
  const float* enorm = (const float*)d_in[2];
  const int* etype = (const int*)d_in[3];
  const float* wcomp = (const float*)d_in[4];
  const float* bases = (const float*)d_in[5];
  const float* loopw = (const float*)d_in[6];
  const float* bias1 = (const float*)d_in[7];
  const float* W2 = (const float*)d_in[8];
  const float* bias2 = (const float*)d_in[9];
  float* out = (float*)d_out;
  const int* srcA = EI;
  const int* dstA = EI + EE;

  char* p = (char*)d_ws;
  auto alloc = [&](size_t bytes) {
    char* r = p;
    p += (bytes + 255) & ~(size_t)255;
    return r;
  };
  unsigned short* xw  = (unsigned short*)alloc((size_t)NN * NJ * 2);  // 115.2 MB
  unsigned short* Xbf = (unsigned short*)alloc((size_t)NN * 128 * 2);
  unsigned short* hs  = (unsigned short*)alloc((size_t)NN * 128 * 2);
  unsigned short* zb  = (unsigned short*)alloc((size_t)NN * 128 * 2);
  unsigned short* Wt  = (unsigned short*)alloc((size_t)NJ * 128 * 2);
  unsigned short* W2t = (unsigned short*)alloc(128 * 128 * 2);
  int* pdin    = (int*)alloc((size_t)NSLICE * NPAD * 4);
  int* pdout   = (int*)alloc((size_t)NSLICE * NPAD * 4);
  int* din     = (int*)alloc((size_t)NPAD * 4);
  int* dout    = (int*)alloc((size_t)NPAD * 4);
  int* row_ptr = (int*)alloc((size_t)(NPAD + 1) * 4);
  int* cursor  = (int*)alloc((size_t)NN * 4);
  int* bsum    = (int*)alloc((size_t)NSB * 4);
  int2* em1    = (int2*)alloc((size_t)EE * 8);
  int2* em2    = (int2*)alloc((size_t)EE * 8);

  hipLaunchKernelGGL(k_prep, dim3(576), dim3(256), 0, stream, wcomp, bases, loopw, W2, Wt, W2t);
  hipLaunchKernelGGL(k_xbf, dim3(6250), dim3(256), 0, stream, X, Xbf);
  hipLaunchKernelGGL(k_hist, dim3(256), dim3(256), 0, stream, EI, pdin, pdout);
  hipLaunchKernelGGL(k_scan_a, dim3(NSB), dim3(256), 0, stream, pdin, pdout, din, dout, bsum);
  hipLaunchKernelGGL(k_scan_b, dim3(1), dim3(64), 0, stream, bsum, row_ptr);
  hipLaunchKernelGGL(k_scan_c, dim3(NSB), dim3(256), 0, stream, din, bsum, row_ptr, cursor);
  hipLaunchKernelGGL(k_csr, dim3(3125), dim3(256), 0, stream,
                     srcA, dstA, etype, enorm, cursor, em1, em2);
  hipLaunchKernelGGL(k_gemm, dim3(391, 9), dim3(256), 0, stream,
                     Xbf, Wt, xw, (float*)nullptr, (const float*)nullptr, NN, NJ);
  hipLaunchKernelGGL(k_agg1, dim3(12500), dim3(256), 0, stream,
                     xw, em1, row_ptr, dout, bias1, hs);
  hipLaunchKernelGGL(k_agg2, dim3(12500), dim3(256), 0, stream,
                     hs, em2, row_ptr, zb);
  hipLaunchKernelGGL(k_gemm, dim3(391, 1), dim3(256), 0, stream,
                     zb, W2t, (unsigned short*)nullptr, out, bias2, NN, 128);
}

// Round 6
// 340.235 us; speedup vs baseline: 1.4095x; 1.0707x over previous
//
#include <hip/hip_runtime.h>

#define NN 50000
#define EE 800000
#define NB 30
#define NJ 1152   // 8 relations * 128 + 128 loop cols
#define NSB 49    // scan blocks: 49*1024 = 50176 nodes covered
#define NPART 16
#define RANGE 3136     // NPART*RANGE = 50176 >= NN
#define NSLICE 64
#define ESL 12500      // EE / NSLICE
#define NPAD 50176

typedef __attribute__((ext_vector_type(8))) short short8;
typedef __attribute__((ext_vector_type(4))) float f32x4;

__device__ __forceinline__ unsigned short f2bf(float f) {
  unsigned u = __float_as_uint(f);
  u += 0x7FFF + ((u >> 16) & 1);           // round-to-nearest-even
  return (unsigned short)(u >> 16);
}
__device__ __forceinline__ float bf2f(unsigned short s) {
  return __uint_as_float(((unsigned)s) << 16);
}

// ---- build Wt[j][k] (bf16, j = r*128+o for r<8, j>=1024 -> loop_weight), W2t[o][k] ----
__global__ void k_prep(const float* __restrict__ wcomp, const float* __restrict__ bases,
                       const float* __restrict__ loopw, const float* __restrict__ W2,
                       unsigned short* __restrict__ Wt, unsigned short* __restrict__ W2t) {
  int idx = blockIdx.x * 256 + threadIdx.x;
  if (idx < NJ * 128) {
    int j = idx >> 7, k = idx & 127;
    float v;
    if (j < 1024) {
      int r = j >> 7, o = j & 127;
      float s = 0.f;
#pragma unroll
      for (int b = 0; b < NB; ++b)
        s = fmaf(wcomp[r * NB + b], bases[((size_t)b * 128 + k) * 128 + o], s);
      v = s;
    } else {
      v = loopw[k * 128 + (j - 1024)];
    }
    Wt[idx] = f2bf(v);
  }
  if (idx < 128 * 128) {
    int j = idx >> 7, k = idx & 127;
    W2t[idx] = f2bf(W2[k * 128 + j]);
  }
}

// ---- X (f32) -> bf16 ----
__global__ void k_xbf(const float* __restrict__ X, unsigned short* __restrict__ Xbf) {
  int i = (blockIdx.x * 256 + threadIdx.x) * 4;
  float4 v = *(const float4*)(X + i);
  uint2 o;
  o.x = (unsigned)f2bf(v.x) | ((unsigned)f2bf(v.y) << 16);
  o.y = (unsigned)f2bf(v.z) | ((unsigned)f2bf(v.w) << 16);
  *(uint2*)(Xbf + i) = o;
}

// ---- partitioned LDS degree histograms (no global atomics) ----
// 2048 blocks: bit0 = kind (0: din from dst, 1: dout from src), bits1-6 = slice, bits7+ = partition
__global__ __launch_bounds__(256) void k_hist(const int* __restrict__ EI,
                                              int* __restrict__ pdin, int* __restrict__ pdout) {
  __shared__ int hist[RANGE];
  int b = blockIdx.x;
  int kind = b & 1;
  int sl = (b >> 1) & (NSLICE - 1);
  int r = b >> 7;
  const int base = r * RANGE;
  const int* vals = kind ? EI : EI + EE;   // kind1: src, kind0: dst
  int* part = kind ? pdout : pdin;
  for (int j = threadIdx.x; j < RANGE; j += 256) hist[j] = 0;
  __syncthreads();
  const int e0 = sl * ESL;
  for (int i = threadIdx.x; i < ESL / 4; i += 256) {
    int4 d = *(const int4*)(vals + e0 + i * 4);
    int x;
    x = d.x - base; if ((unsigned)x < RANGE) atomicAdd(&hist[x], 1);
    x = d.y - base; if ((unsigned)x < RANGE) atomicAdd(&hist[x], 1);
    x = d.z - base; if ((unsigned)x < RANGE) atomicAdd(&hist[x], 1);
    x = d.w - base; if ((unsigned)x < RANGE) atomicAdd(&hist[x], 1);
  }
  __syncthreads();
  for (int j = threadIdx.x; j < RANGE; j += 256)
    part[sl * NPAD + base + j] = hist[j];
}

// ---- A) reduce partials (din & dout) + per-block sums of din ----
__global__ __launch_bounds__(256) void k_scan_a(const int* __restrict__ pdin,
                                                const int* __restrict__ pdout,
                                                int* __restrict__ din,
                                                int* __restrict__ dout,
                                                int* __restrict__ bsum) {
  __shared__ int wsum[4];
  int b = blockIdx.x, t = threadIdx.x;
  int lane = t & 63, w = t >> 6;
  int i0 = b * 1024 + t * 4;
  int4 acc = {0, 0, 0, 0}, od = {0, 0, 0, 0};
  for (int sl = 0; sl < NSLICE; ++sl) {
    int4 a = *(const int4*)(pdin + sl * NPAD + i0);
    int4 o = *(const int4*)(pdout + sl * NPAD + i0);
    acc.x += a.x; acc.y += a.y; acc.z += a.z; acc.w += a.w;
    od.x += o.x; od.y += o.y; od.z += o.z; od.w += o.w;
  }
  *(int4*)(din + i0) = acc;
  *(int4*)(dout + i0) = od;
  int sv = acc.x + acc.y + acc.z + acc.w;
#pragma unroll
  for (int off = 32; off; off >>= 1) sv += __shfl_down(sv, off, 64);
  if (lane == 0) wsum[w] = sv;
  __syncthreads();
  if (t == 0) bsum[b] = wsum[0] + wsum[1] + wsum[2] + wsum[3];
}

// ---- B) exclusive scan of the 49 block sums (one wave) ----
__global__ void k_scan_b(int* __restrict__ bsum, int* __restrict__ row_ptr) {
  int t = threadIdx.x;  // 64 threads
  int v = (t < NSB) ? bsum[t] : 0;
  int orig = v;
#pragma unroll
  for (int off = 1; off < 64; off <<= 1) {
    int u = __shfl_up(v, off, 64);
    if (t >= off) v += u;
  }
  if (t < NSB) bsum[t] = v - orig;   // exclusive block offset
  if (t == 0) row_ptr[NN] = EE;
}

// ---- C) block-level exclusive scan + offset -> row_ptr, cursor ----
__global__ __launch_bounds__(256) void k_scan_c(const int* __restrict__ din,
                                                const int* __restrict__ bsum,
                                                int* __restrict__ row_ptr,
                                                int* __restrict__ cursor) {
  __shared__ int wsum[4];
  int b = blockIdx.x, t = threadIdx.x;
  int lane = t & 63, w = t >> 6;
  int i0 = b * 1024 + t * 4;
  int4 d = *(const int4*)(din + i0);
  int sth = d.x + d.y + d.z + d.w;
  int v = sth;
#pragma unroll
  for (int off = 1; off < 64; off <<= 1) {
    int u = __shfl_up(v, off, 64);
    if (lane >= off) v += u;
  }
  if (lane == 63) wsum[w] = v;
  __syncthreads();
  int woff = 0;
  for (int j = 0; j < w; ++j) woff += wsum[j];
  int base = bsum[b] + woff + (v - sth);
  if (i0 + 0 <= NN) { row_ptr[i0 + 0] = base; if (i0 + 0 < NN) cursor[i0 + 0] = base; } base += d.x;
  if (i0 + 1 <= NN) { row_ptr[i0 + 1] = base; if (i0 + 1 < NN) cursor[i0 + 1] = base; } base += d.y;
  if (i0 + 2 <= NN) { row_ptr[i0 + 2] = base; if (i0 + 2 < NN) cursor[i0 + 2] = base; } base += d.z;
  if (i0 + 3 <= NN) { row_ptr[i0 + 3] = base; if (i0 + 3 < NN) cursor[i0 + 3] = base; }
}

// ---- scatter packed edge metadata into dst-CSR order (global atomic cursor) ----
__global__ void k_csr(const int* __restrict__ src, const int* __restrict__ dst,
                      const int* __restrict__ ety, const float* __restrict__ enorm,
                      int* __restrict__ cursor,
                      int2* __restrict__ em1, int2* __restrict__ em2) {
  int e = blockIdx.x * 256 + threadIdx.x;
  if (e < EE) {
    int pos = atomicAdd(&cursor[dst[e]], 1);
    int s = src[e];
    int wb = __float_as_int(enorm[e]);
    em1[pos] = make_int2(s * NJ + ety[e] * 128, wb);
    em2[pos] = make_int2(s * 128, wb);
  }
}

// ---- bf16 MFMA GEMM: C[M][ldc] = A[M][128] * B^T (B given as [Ncols][128]) ----
__global__ __launch_bounds__(256) void k_gemm(const unsigned short* __restrict__ A,
                                              const unsigned short* __restrict__ B,
                                              unsigned short* __restrict__ Cbf,
                                              float* __restrict__ Cf,
                                              const float* __restrict__ bias,
                                              int M, int ldc) {
  __shared__ unsigned short As[128 * 136];   // row stride 272 B
  __shared__ unsigned short Bs[128 * 136];
  const int m0 = blockIdx.x * 128, j0 = blockIdx.y * 128;
  const int t = threadIdx.x;
  for (int i = t; i < 2048; i += 256) {
    int r = i >> 4, c = i & 15;
    uint4 va = {0, 0, 0, 0};
    int gr = m0 + r;
    if (gr < M) va = *(const uint4*)(A + (size_t)gr * 128 + c * 8);
    *(uint4*)(&As[r * 136 + c * 8]) = va;
    uint4 vb = *(const uint4*)(B + (size_t)(j0 + r) * 128 + c * 8);
    *(uint4*)(&Bs[r * 136 + c * 8]) = vb;
  }
  __syncthreads();

  const int lane = t & 63, wave = t >> 6;
  const int wr = (wave >> 1) * 64, wc = (wave & 1) * 64;
  const int lr = lane & 15, lk = (lane >> 4) * 8;

  f32x4 acc[4][4];
#pragma unroll
  for (int m = 0; m < 4; ++m)
#pragma unroll
    for (int n = 0; n < 4; ++n) acc[m][n] = (f32x4){0.f, 0.f, 0.f, 0.f};

#pragma unroll
  for (int kt = 0; kt < 4; ++kt) {
    short8 af[4], bfr[4];
#pragma unroll
    for (int m = 0; m < 4; ++m)
      af[m] = *(const short8*)(&As[(wr + m * 16 + lr) * 136 + kt * 32 + lk]);
#pragma unroll
    for (int n = 0; n < 4; ++n)
      bfr[n] = *(const short8*)(&Bs[(wc + n * 16 + lr) * 136 + kt * 32 + lk]);
#pragma unroll
    for (int m = 0; m < 4; ++m)
#pragma unroll
      for (int n = 0; n < 4; ++n)
        acc[m][n] = __builtin_amdgcn_mfma_f32_16x16x32_bf16(af[m], bfr[n], acc[m][n], 0, 0, 0);
  }

#pragma unroll
  for (int m = 0; m < 4; ++m) {
    int rbase = m0 + wr + m * 16 + (lane >> 4) * 4;
#pragma unroll
    for (int i = 0; i < 4; ++i) {
      int row = rbase + i;
      if (row >= M) continue;
      if (Cbf) {
        unsigned short* cr = Cbf + (size_t)row * ldc + j0 + wc;
#pragma unroll
        for (int n = 0; n < 4; ++n) cr[n * 16 + lr] = f2bf(acc[m][n][i]);
      } else {
        float* cr = Cf + (size_t)row * ldc + j0 + wc;
#pragma unroll
        for (int n = 0; n < 4; ++n) cr[n * 16 + lr] = acc[m][n][i] + bias[j0 + wc + n * 16 + lr];
      }
    }
  }
}

#define UNR 8

// ---- layer-1 aggregation: wave per dst node, 8-wide ILP unroll ----
__global__ __launch_bounds__(256) void k_agg1(const unsigned short* __restrict__ xw,
                                              const int2* __restrict__ em1,
                                              const int* __restrict__ row_ptr,
                                              const int* __restrict__ deg_out,
                                              const float* __restrict__ bias1,
                                              unsigned short* __restrict__ hs) {
  int gw = (blockIdx.x * blockDim.x + threadIdx.x) >> 6;
  int lane = threadIdx.x & 63;
  if (gw >= NN) return;
  int beg = row_ptr[gw], end = row_ptr[gw + 1];
  float a0 = 0.f, a1 = 0.f;
  for (int i = beg; i < end; i += UNR) {
    int2 md[UNR];
    unsigned v[UNR];
#pragma unroll
    for (int j = 0; j < UNR; ++j) {
      int idx = i + j;
      idx = idx < end ? idx : end - 1;          // pad: duplicate last edge (MSHR-merged)
      md[j] = em1[idx];
      if (i + j >= end) md[j].y = 0;            // pad weight = 0
    }
#pragma unroll
    for (int j = 0; j < UNR; ++j)
      v[j] = *(const unsigned*)(xw + (size_t)(unsigned)md[j].x + lane * 2);
#pragma unroll
    for (int j = 0; j < UNR; ++j) {
      float w = __int_as_float(md[j].y);
      a0 = fmaf(w, bf2f((unsigned short)(v[j] & 0xffff)), a0);
      a1 = fmaf(w, bf2f((unsigned short)(v[j] >> 16)), a1);
    }
  }
  unsigned vl = *(const unsigned*)(xw + (size_t)gw * NJ + 1024 + lane * 2);
  float ns = rsqrtf(fmaxf((float)deg_out[gw], 1.f));
  float h0 = (a0 + bf2f((unsigned short)(vl & 0xffff)) + bias1[lane * 2]) * ns;
  float h1 = (a1 + bf2f((unsigned short)(vl >> 16)) + bias1[lane * 2 + 1]) * ns;
  unsigned o = (unsigned)f2bf(h0) | ((unsigned)f2bf(h1) << 16);
  *(unsigned*)(hs + (size_t)gw * 128 + lane * 2) = o;
}

// ---- layer-2 aggregation: same structure over hs ----
__global__ __launch_bounds__(256) void k_agg2(const unsigned short* __restrict__ hs,
                                              const int2* __restrict__ em2,
                                              const int* __restrict__ row_ptr,
                                              unsigned short* __restrict__ zb) {
  int gw = (blockIdx.x * blockDim.x + threadIdx.x) >> 6;
  int lane = threadIdx.x & 63;
  if (gw >= NN) return;
  int beg = row_ptr[gw], end = row_ptr[gw + 1];
  float a0 = 0.f, a1 = 0.f;
  for (int i = beg; i < end; i += UNR) {
    int2 md[UNR];
    unsigned v[UNR];
#pragma unroll
    for (int j = 0; j < UNR; ++j) {
      int idx = i + j;
      idx = idx < end ? idx : end - 1;
      md[j] = em2[idx];
      if (i + j >= end) md[j].y = 0;
    }
#pragma unroll
    for (int j = 0; j < UNR; ++j)
      v[j] = *(const unsigned*)(hs + (size_t)(unsigned)md[j].x + lane * 2);
#pragma unroll
    for (int j = 0; j < UNR; ++j) {
      float w = __int_as_float(md[j].y);
      a0 = fmaf(w, bf2f((unsigned short)(v[j] & 0xffff)), a0);
      a1 = fmaf(w, bf2f((unsigned short)(v[j] >> 16)), a1);
    }
  }
  float nd = rsqrtf(fmaxf((float)(end - beg), 1.f));
  unsigned o = (unsigned)f2bf(a0 * nd) | ((unsigned)f2bf(a1 * nd) << 16);
  *(unsigned*)(zb + (size_t)gw * 128 + lane * 2) = o;
}

extern "C" void kernel_launch(void* const* d_in, const int* in_sizes, int n_in,
                              void* d_out, int out_size, void* d_ws, size_t ws_size,
                              hipStream_t stream) {
  const float* X = (const float*)d_in[0];
  const int* EI = (const int*)d_in[1];
  const float* enorm = (const float*)d_in[2];
  const int* etype = (const int*)d_in[3];
  const float* wcomp = (const float*)d_in[4];
  const float* bases = (const float*)d_in[5];
  const float* loopw = (const float*)d_in[6];
  const float* bias1 = (const float*)d_in[7];
  const float* W2 = (const float*)d_in[8];
  const float* bias2 = (const float*)d_in[9];
  float* out = (float*)d_out;
  const int* srcA = EI;
  const int* dstA = EI + EE;

  char* p = (char*)d_ws;
  auto alloc = [&](size_t bytes) {
    char* r = p;
    p += (bytes + 255) & ~(size_t)255;
    return r;
  };
  unsigned short* xw  = (unsigned short*)alloc((size_t)NN * NJ * 2);  // 115.2 MB
  unsigned short* Xbf = (unsigned short*)alloc((size_t)NN * 128 * 2);
  unsigned short* hs  = (unsigned short*)alloc((size_t)NN * 128 * 2);
  unsigned short* zb  = (unsigned short*)alloc((size_t)NN * 128 * 2);
  unsigned short* Wt  = (unsigned short*)alloc((size_t)NJ * 128 * 2);
  unsigned short* W2t = (unsigned short*)alloc(128 * 128 * 2);
  int* pdin    = (int*)alloc((size_t)NSLICE * NPAD * 4);
  int* pdout   = (int*)alloc((size_t)NSLICE * NPAD * 4);
  int* din     = (int*)alloc((size_t)NPAD * 4);
  int* dout    = (int*)alloc((size_t)NPAD * 4);
  int* row_ptr = (int*)alloc((size_t)(NPAD + 1) * 4);
  int* cursor  = (int*)alloc((size_t)NN * 4);
  int* bsum    = (int*)alloc((size_t)NSB * 4);
  int2* em1    = (int2*)alloc((size_t)EE * 8);
  int2* em2    = (int2*)alloc((size_t)EE * 8);

  hipLaunchKernelGGL(k_prep, dim3(576), dim3(256), 0, stream, wcomp, bases, loopw, W2, Wt, W2t);
  hipLaunchKernelGGL(k_xbf, dim3(6250), dim3(256), 0, stream, X, Xbf);
  hipLaunchKernelGGL(k_hist, dim3(2048), dim3(256), 0, stream, EI, pdin, pdout);
  hipLaunchKernelGGL(k_scan_a, dim3(NSB), dim3(256), 0, stream, pdin, pdout, din, dout, bsum);
  hipLaunchKernelGGL(k_scan_b, dim3(1), dim3(64), 0, stream, bsum, row_ptr);
  hipLaunchKernelGGL(k_scan_c, dim3(NSB), dim3(256), 0, stream, din, bsum, row_ptr, cursor);
  hipLaunchKernelGGL(k_csr, dim3(3125), dim3(256), 0, stream,
                     srcA, dstA, etype, enorm, cursor, em1, em2);
  hipLaunchKernelGGL(k_gemm, dim3(391, 9), dim3(256), 0, stream,
                     Xbf, Wt, xw, (float*)nullptr, (const float*)nullptr, NN, NJ);
  hipLaunchKernelGGL(k_agg1, dim3(12500), dim3(256), 0, stream,
                     xw, em1, row_ptr, dout, bias1, hs);
  hipLaunchKernelGGL(k_agg2, dim3(12500), dim3(256), 0, stream,
                     hs, em2, row_ptr, zb);
  hipLaunchKernelGGL(k_gemm, dim3(391, 1), dim3(256), 0, stream,
                     zb, W2t, (unsigned short*)nullptr, out, bias2, NN, 128);
}

// Round 7
// 330.011 us; speedup vs baseline: 1.4531x; 1.0310x over previous
//
#include <hip/hip_runtime.h>

#define NN 50000
#define EE 800000
#define NB 30
#define NJ 1152   // 8 relations * 128 + 128 loop cols
#define NSB 49    // scan blocks: 49*1024 = 50176 nodes covered
#define NPART 16
#define RANGE 3136     // NPART*RANGE = 50176 >= NN
#define NSLICE 64
#define ESL 12500      // EE / NSLICE
#define NPAD 50176

typedef __attribute__((ext_vector_type(8))) short short8;
typedef __attribute__((ext_vector_type(4))) float f32x4;

__device__ __forceinline__ unsigned short f2bf(float f) {
  unsigned u = __float_as_uint(f);
  u += 0x7FFF + ((u >> 16) & 1);           // round-to-nearest-even
  return (unsigned short)(u >> 16);
}
__device__ __forceinline__ float bf2f(unsigned short s) {
  return __uint_as_float(((unsigned)s) << 16);
}

// ---- fused: build Wt/W2t (blocks 0..575) + X->bf16 (blocks 576..6825) ----
__global__ __launch_bounds__(256) void k_prep(const float* __restrict__ wcomp,
                                              const float* __restrict__ bases,
                                              const float* __restrict__ loopw,
                                              const float* __restrict__ W2,
                                              const float* __restrict__ X,
                                              unsigned short* __restrict__ Wt,
                                              unsigned short* __restrict__ W2t,
                                              unsigned short* __restrict__ Xbf) {
  int b = blockIdx.x;
  if (b < 576) {
    int idx = b * 256 + threadIdx.x;
    int j = idx >> 7, k = idx & 127;
    float v;
    if (j < 1024) {
      int r = j >> 7, o = j & 127;
      float s = 0.f;
#pragma unroll
      for (int bb = 0; bb < NB; ++bb)
        s = fmaf(wcomp[r * NB + bb], bases[((size_t)bb * 128 + k) * 128 + o], s);
      v = s;
    } else {
      v = loopw[k * 128 + (j - 1024)];
    }
    Wt[idx] = f2bf(v);
    if (idx < 128 * 128) W2t[idx] = f2bf(W2[k * 128 + j]);
  } else {
    int i = ((b - 576) * 256 + threadIdx.x) * 4;
    float4 v = *(const float4*)(X + i);
    uint2 o;
    o.x = (unsigned)f2bf(v.x) | ((unsigned)f2bf(v.y) << 16);
    o.y = (unsigned)f2bf(v.z) | ((unsigned)f2bf(v.w) << 16);
    *(uint2*)(Xbf + i) = o;
  }
}

// ---- partitioned LDS degree histograms (no global atomics) ----
// 2048 blocks: bit0 = kind (0: din from dst, 1: dout from src), bits1-6 = slice, bits7+ = partition
__global__ __launch_bounds__(256) void k_hist(const int* __restrict__ EI,
                                              int* __restrict__ pdin, int* __restrict__ pdout) {
  __shared__ int hist[RANGE];
  int b = blockIdx.x;
  int kind = b & 1;
  int sl = (b >> 1) & (NSLICE - 1);
  int r = b >> 7;
  const int base = r * RANGE;
  const int* vals = kind ? EI : EI + EE;   // kind1: src, kind0: dst
  int* part = kind ? pdout : pdin;
  for (int j = threadIdx.x; j < RANGE; j += 256) hist[j] = 0;
  __syncthreads();
  const int e0 = sl * ESL;
  for (int i = threadIdx.x; i < ESL / 4; i += 256) {
    int4 d = *(const int4*)(vals + e0 + i * 4);
    int x;
    x = d.x - base; if ((unsigned)x < RANGE) atomicAdd(&hist[x], 1);
    x = d.y - base; if ((unsigned)x < RANGE) atomicAdd(&hist[x], 1);
    x = d.z - base; if ((unsigned)x < RANGE) atomicAdd(&hist[x], 1);
    x = d.w - base; if ((unsigned)x < RANGE) atomicAdd(&hist[x], 1);
  }
  __syncthreads();
  for (int j = threadIdx.x; j < RANGE; j += 256)
    part[sl * NPAD + base + j] = hist[j];
}

// ---- A) reduce partials (din & dout) + per-block sums of din ----
__global__ __launch_bounds__(256) void k_scan_a(const int* __restrict__ pdin,
                                                const int* __restrict__ pdout,
                                                int* __restrict__ din,
                                                int* __restrict__ dout,
                                                int* __restrict__ bsum) {
  __shared__ int wsum[4];
  int b = blockIdx.x, t = threadIdx.x;
  int lane = t & 63, w = t >> 6;
  int i0 = b * 1024 + t * 4;
  int4 acc = {0, 0, 0, 0}, od = {0, 0, 0, 0};
  for (int sl = 0; sl < NSLICE; ++sl) {
    int4 a = *(const int4*)(pdin + sl * NPAD + i0);
    int4 o = *(const int4*)(pdout + sl * NPAD + i0);
    acc.x += a.x; acc.y += a.y; acc.z += a.z; acc.w += a.w;
    od.x += o.x; od.y += o.y; od.z += o.z; od.w += o.w;
  }
  *(int4*)(din + i0) = acc;
  *(int4*)(dout + i0) = od;
  int sv = acc.x + acc.y + acc.z + acc.w;
#pragma unroll
  for (int off = 32; off; off >>= 1) sv += __shfl_down(sv, off, 64);
  if (lane == 0) wsum[w] = sv;
  __syncthreads();
  if (t == 0) bsum[b] = wsum[0] + wsum[1] + wsum[2] + wsum[3];
}

// ---- B) exclusive scan of the 49 block sums (one wave) ----
__global__ void k_scan_b(int* __restrict__ bsum, int* __restrict__ row_ptr) {
  int t = threadIdx.x;  // 64 threads
  int v = (t < NSB) ? bsum[t] : 0;
  int orig = v;
#pragma unroll
  for (int off = 1; off < 64; off <<= 1) {
    int u = __shfl_up(v, off, 64);
    if (t >= off) v += u;
  }
  if (t < NSB) bsum[t] = v - orig;   // exclusive block offset
  if (t == 0) row_ptr[NN] = EE;
}

// ---- C) block-level exclusive scan + offset -> row_ptr, cursor ----
__global__ __launch_bounds__(256) void k_scan_c(const int* __restrict__ din,
                                                const int* __restrict__ bsum,
                                                int* __restrict__ row_ptr,
                                                int* __restrict__ cursor) {
  __shared__ int wsum[4];
  int b = blockIdx.x, t = threadIdx.x;
  int lane = t & 63, w = t >> 6;
  int i0 = b * 1024 + t * 4;
  int4 d = *(const int4*)(din + i0);
  int sth = d.x + d.y + d.z + d.w;
  int v = sth;
#pragma unroll
  for (int off = 1; off < 64; off <<= 1) {
    int u = __shfl_up(v, off, 64);
    if (lane >= off) v += u;
  }
  if (lane == 63) wsum[w] = v;
  __syncthreads();
  int woff = 0;
  for (int j = 0; j < w; ++j) woff += wsum[j];
  int base = bsum[b] + woff + (v - sth);
  if (i0 + 0 <= NN) { row_ptr[i0 + 0] = base; if (i0 + 0 < NN) cursor[i0 + 0] = base; } base += d.x;
  if (i0 + 1 <= NN) { row_ptr[i0 + 1] = base; if (i0 + 1 < NN) cursor[i0 + 1] = base; } base += d.y;
  if (i0 + 2 <= NN) { row_ptr[i0 + 2] = base; if (i0 + 2 < NN) cursor[i0 + 2] = base; } base += d.z;
  if (i0 + 3 <= NN) { row_ptr[i0 + 3] = base; if (i0 + 3 < NN) cursor[i0 + 3] = base; }
}

// ---- scatter packed edge metadata into dst-CSR order (global atomic cursor) ----
// em1 = {128*(9*src + ety), enorm bits}; agg2 derives src via /9
__global__ void k_csr(const int* __restrict__ src, const int* __restrict__ dst,
                      const int* __restrict__ ety, const float* __restrict__ enorm,
                      int* __restrict__ cursor, int2* __restrict__ em1) {
  int e = blockIdx.x * 256 + threadIdx.x;
  if (e < EE) {
    int pos = atomicAdd(&cursor[dst[e]], 1);
    int s = src[e];
    int wb = __float_as_int(enorm[e]);
    em1[pos] = make_int2(s * NJ + ety[e] * 128, wb);
  }
}

// ---- bf16 MFMA GEMM: C[M][ldc] = A[M][128] * B^T (B given as [Ncols][128]) ----
__global__ __launch_bounds__(256) void k_gemm(const unsigned short* __restrict__ A,
                                              const unsigned short* __restrict__ B,
                                              unsigned short* __restrict__ Cbf,
                                              float* __restrict__ Cf,
                                              const float* __restrict__ bias,
                                              int M, int ldc) {
  __shared__ unsigned short As[128 * 136];   // row stride 272 B
  __shared__ unsigned short Bs[128 * 136];
  const int m0 = blockIdx.x * 128, j0 = blockIdx.y * 128;
  const int t = threadIdx.x;
  for (int i = t; i < 2048; i += 256) {
    int r = i >> 4, c = i & 15;
    uint4 va = {0, 0, 0, 0};
    int gr = m0 + r;
    if (gr < M) va = *(const uint4*)(A + (size_t)gr * 128 + c * 8);
    *(uint4*)(&As[r * 136 + c * 8]) = va;
    uint4 vb = *(const uint4*)(B + (size_t)(j0 + r) * 128 + c * 8);
    *(uint4*)(&Bs[r * 136 + c * 8]) = vb;
  }
  __syncthreads();

  const int lane = t & 63, wave = t >> 6;
  const int wr = (wave >> 1) * 64, wc = (wave & 1) * 64;
  const int lr = lane & 15, lk = (lane >> 4) * 8;

  f32x4 acc[4][4];
#pragma unroll
  for (int m = 0; m < 4; ++m)
#pragma unroll
    for (int n = 0; n < 4; ++n) acc[m][n] = (f32x4){0.f, 0.f, 0.f, 0.f};

#pragma unroll
  for (int kt = 0; kt < 4; ++kt) {
    short8 af[4], bfr[4];
#pragma unroll
    for (int m = 0; m < 4; ++m)
      af[m] = *(const short8*)(&As[(wr + m * 16 + lr) * 136 + kt * 32 + lk]);
#pragma unroll
    for (int n = 0; n < 4; ++n)
      bfr[n] = *(const short8*)(&Bs[(wc + n * 16 + lr) * 136 + kt * 32 + lk]);
#pragma unroll
    for (int m = 0; m < 4; ++m)
#pragma unroll
      for (int n = 0; n < 4; ++n)
        acc[m][n] = __builtin_amdgcn_mfma_f32_16x16x32_bf16(af[m], bfr[n], acc[m][n], 0, 0, 0);
  }

#pragma unroll
  for (int m = 0; m < 4; ++m) {
    int rbase = m0 + wr + m * 16 + (lane >> 4) * 4;
#pragma unroll
    for (int i = 0; i < 4; ++i) {
      int row = rbase + i;
      if (row >= M) continue;
      if (Cbf) {
        unsigned short* cr = Cbf + (size_t)row * ldc + j0 + wc;
#pragma unroll
        for (int n = 0; n < 4; ++n) cr[n * 16 + lr] = f2bf(acc[m][n][i]);
      } else {
        float* cr = Cf + (size_t)row * ldc + j0 + wc;
#pragma unroll
        for (int n = 0; n < 4; ++n) cr[n * 16 + lr] = acc[m][n][i] + bias[j0 + wc + n * 16 + lr];
      }
    }
  }
}

#define UNR 8

// ---- layer-1 aggregation: wave per dst node, 8-wide ILP unroll ----
__global__ __launch_bounds__(256) void k_agg1(const unsigned short* __restrict__ xw,
                                              const int2* __restrict__ em1,
                                              const int* __restrict__ row_ptr,
                                              const int* __restrict__ deg_out,
                                              const float* __restrict__ bias1,
                                              unsigned short* __restrict__ hs) {
  int gw = (blockIdx.x * blockDim.x + threadIdx.x) >> 6;
  int lane = threadIdx.x & 63;
  if (gw >= NN) return;
  int beg = row_ptr[gw], end = row_ptr[gw + 1];
  float a0 = 0.f, a1 = 0.f;
  for (int i = beg; i < end; i += UNR) {
    int2 md[UNR];
    unsigned v[UNR];
#pragma unroll
    for (int j = 0; j < UNR; ++j) {
      int idx = i + j;
      idx = idx < end ? idx : end - 1;          // pad: duplicate last edge (MSHR-merged)
      md[j] = em1[idx];
      if (i + j >= end) md[j].y = 0;            // pad weight = 0
    }
#pragma unroll
    for (int j = 0; j < UNR; ++j)
      v[j] = *(const unsigned*)(xw + (size_t)(unsigned)md[j].x + lane * 2);
#pragma unroll
    for (int j = 0; j < UNR; ++j) {
      float w = __int_as_float(md[j].y);
      a0 = fmaf(w, bf2f((unsigned short)(v[j] & 0xffff)), a0);
      a1 = fmaf(w, bf2f((unsigned short)(v[j] >> 16)), a1);
    }
  }
  unsigned vl = *(const unsigned*)(xw + (size_t)gw * NJ + 1024 + lane * 2);
  float ns = rsqrtf(fmaxf((float)deg_out[gw], 1.f));
  float h0 = (a0 + bf2f((unsigned short)(vl & 0xffff)) + bias1[lane * 2]) * ns;
  float h1 = (a1 + bf2f((unsigned short)(vl >> 16)) + bias1[lane * 2 + 1]) * ns;
  unsigned o = (unsigned)f2bf(h0) | ((unsigned)f2bf(h1) << 16);
  *(unsigned*)(hs + (size_t)gw * 128 + lane * 2) = o;
}

// ---- layer-2 aggregation: derives src from em1.x (src = (x>>7)/9) ----
__global__ __launch_bounds__(256) void k_agg2(const unsigned short* __restrict__ hs,
                                              const int2* __restrict__ em1,
                                              const int* __restrict__ row_ptr,
                                              unsigned short* __restrict__ zb) {
  int gw = (blockIdx.x * blockDim.x + threadIdx.x) >> 6;
  int lane = threadIdx.x & 63;
  if (gw >= NN) return;
  int beg = row_ptr[gw], end = row_ptr[gw + 1];
  float a0 = 0.f, a1 = 0.f;
  for (int i = beg; i < end; i += UNR) {
    int2 md[UNR];
    unsigned v[UNR];
#pragma unroll
    for (int j = 0; j < UNR; ++j) {
      int idx = i + j;
      idx = idx < end ? idx : end - 1;
      md[j] = em1[idx];
      if (i + j >= end) md[j].y = 0;
    }
#pragma unroll
    for (int j = 0; j < UNR; ++j) {
      unsigned srcn = (((unsigned)md[j].x) >> 7) / 9u;   // magic-mul division
      v[j] = *(const unsigned*)(hs + ((size_t)srcn << 7) + lane * 2);
    }
#pragma unroll
    for (int j = 0; j < UNR; ++j) {
      float w = __int_as_float(md[j].y);
      a0 = fmaf(w, bf2f((unsigned short)(v[j] & 0xffff)), a0);
      a1 = fmaf(w, bf2f((unsigned short)(v[j] >> 16)), a1);
    }
  }
  float nd = rsqrtf(fmaxf((float)(end - beg), 1.f));
  unsigned o = (unsigned)f2bf(a0 * nd) | ((unsigned)f2bf(a1 * nd) << 16);
  *(unsigned*)(zb + (size_t)gw * 128 + lane * 2) = o;
}

extern "C" void kernel_launch(void* const* d_in, const int* in_sizes, int n_in,
                              void* d_out, int out_size, void* d_ws, size_t ws_size,
                              hipStream_t stream) {
  const float* X = (const float*)d_in[0];
  const int* EI = (const int*)d_in[1];
  const float* enorm = (const float*)d_in[2];
  const int* etype = (const int*)d_in[3];
  const float* wcomp = (const float*)d_in[4];
  const float* bases = (const float*)d_in[5];
  const float* loopw = (const float*)d_in[6];
  const float* bias1 = (const float*)d_in[7];
  const float* W2 = (const float*)d_in[8];
  const float* bias2 = (const float*)d_in[9];
  float* out = (float*)d_out;
  const int* srcA = EI;
  const int* dstA = EI + EE;

  char* p = (char*)d_ws;
  auto alloc = [&](size_t bytes) {
    char* r = p;
    p += (bytes + 255) & ~(size_t)255;
    return r;
  };
  unsigned short* xw  = (unsigned short*)alloc((size_t)NN * NJ * 2);  // 115.2 MB
  unsigned short* Xbf = (unsigned short*)alloc((size_t)NN * 128 * 2);
  unsigned short* hs  = (unsigned short*)alloc((size_t)NN * 128 * 2);
  unsigned short* zb  = (unsigned short*)alloc((size_t)NN * 128 * 2);
  unsigned short* Wt  = (unsigned short*)alloc((size_t)NJ * 128 * 2);
  unsigned short* W2t = (unsigned short*)alloc(128 * 128 * 2);
  int* pdin    = (int*)alloc((size_t)NSLICE * NPAD * 4);
  int* pdout   = (int*)alloc((size_t)NSLICE * NPAD * 4);
  int* din     = (int*)alloc((size_t)NPAD * 4);
  int* dout    = (int*)alloc((size_t)NPAD * 4);
  int* row_ptr = (int*)alloc((size_t)(NPAD + 1) * 4);
  int* cursor  = (int*)alloc((size_t)NN * 4);
  int* bsum    = (int*)alloc((size_t)NSB * 4);
  int2* em1    = (int2*)alloc((size_t)EE * 8);

  hipLaunchKernelGGL(k_prep, dim3(6826), dim3(256), 0, stream,
                     wcomp, bases, loopw, W2, X, Wt, W2t, Xbf);
  hipLaunchKernelGGL(k_hist, dim3(2048), dim3(256), 0, stream, EI, pdin, pdout);
  hipLaunchKernelGGL(k_scan_a, dim3(NSB), dim3(256), 0, stream, pdin, pdout, din, dout, bsum);
  hipLaunchKernelGGL(k_scan_b, dim3(1), dim3(64), 0, stream, bsum, row_ptr);
  hipLaunchKernelGGL(k_scan_c, dim3(NSB), dim3(256), 0, stream, din, bsum, row_ptr, cursor);
  hipLaunchKernelGGL(k_csr, dim3(3125), dim3(256), 0, stream,
                     srcA, dstA, etype, enorm, cursor, em1);
  hipLaunchKernelGGL(k_gemm, dim3(391, 9), dim3(256), 0, stream,
                     Xbf, Wt, xw, (float*)nullptr, (const float*)nullptr, NN, NJ);
  hipLaunchKernelGGL(k_agg1, dim3(12500), dim3(256), 0, stream,
                     xw, em1, row_ptr, dout, bias1, hs);
  hipLaunchKernelGGL(k_agg2, dim3(12500), dim3(256), 0, stream,
                     hs, em1, row_ptr, zb);
  hipLaunchKernelGGL(k_gemm, dim3(391, 1), dim3(256), 0, stream,
                     zb, W2t, (unsigned short*)nullptr, out, bias2, NN, 128);
}

// Round 8
// 325.314 us; speedup vs baseline: 1.4741x; 1.0144x over previous
//
#include <hip/hip_runtime.h>

#define NN 50000
#define EE 800000
#define NB 30
#define NJ 1152   // 8 relations * 128 + 128 loop cols
#define NSB 49    // scan blocks: 49*1024 = 50176 nodes covered
#define NPART 16
#define RANGE 3136     // NPART*RANGE = 50176 >= NN
#define NSLICE 64
#define ESL 12500      // EE / NSLICE
#define NPAD 50176

typedef __attribute__((ext_vector_type(8))) short short8;
typedef __attribute__((ext_vector_type(4))) float f32x4;

__device__ __forceinline__ unsigned short f2bf(float f) {
  unsigned u = __float_as_uint(f);
  u += 0x7FFF + ((u >> 16) & 1);           // round-to-nearest-even
  return (unsigned short)(u >> 16);
}
__device__ __forceinline__ float bf2f(unsigned short s) {
  return __uint_as_float(((unsigned)s) << 16);
}

// ---- fused: build Wt/W2t (blocks 0..575) + X->bf16 (blocks 576..6825) ----
__global__ __launch_bounds__(256) void k_prep(const float* __restrict__ wcomp,
                                              const float* __restrict__ bases,
                                              const float* __restrict__ loopw,
                                              const float* __restrict__ W2,
                                              const float* __restrict__ X,
                                              unsigned short* __restrict__ Wt,
                                              unsigned short* __restrict__ W2t,
                                              unsigned short* __restrict__ Xbf) {
  int b = blockIdx.x;
  if (b < 576) {
    int idx = b * 256 + threadIdx.x;
    int j = idx >> 7, k = idx & 127;
    float v;
    if (j < 1024) {
      int r = j >> 7, o = j & 127;
      float s = 0.f;
#pragma unroll
      for (int bb = 0; bb < NB; ++bb)
        s = fmaf(wcomp[r * NB + bb], bases[((size_t)bb * 128 + k) * 128 + o], s);
      v = s;
    } else {
      v = loopw[k * 128 + (j - 1024)];
    }
    Wt[idx] = f2bf(v);
    if (idx < 128 * 128) W2t[idx] = f2bf(W2[k * 128 + j]);
  } else {
    int i = ((b - 576) * 256 + threadIdx.x) * 4;
    float4 v = *(const float4*)(X + i);
    uint2 o;
    o.x = (unsigned)f2bf(v.x) | ((unsigned)f2bf(v.y) << 16);
    o.y = (unsigned)f2bf(v.z) | ((unsigned)f2bf(v.w) << 16);
    *(uint2*)(Xbf + i) = o;
  }
}

// ---- partitioned LDS degree histograms (no global atomics) ----
// 2048 blocks: bit0 = kind (0: din from dst, 1: dout from src), bits1-6 = slice, bits7+ = partition
__global__ __launch_bounds__(256) void k_hist(const int* __restrict__ EI,
                                              int* __restrict__ pdin, int* __restrict__ pdout) {
  __shared__ int hist[RANGE];
  int b = blockIdx.x;
  int kind = b & 1;
  int sl = (b >> 1) & (NSLICE - 1);
  int r = b >> 7;
  const int base = r * RANGE;
  const int* vals = kind ? EI : EI + EE;   // kind1: src, kind0: dst
  int* part = kind ? pdout : pdin;
  for (int j = threadIdx.x; j < RANGE; j += 256) hist[j] = 0;
  __syncthreads();
  const int e0 = sl * ESL;
  for (int i = threadIdx.x; i < ESL / 4; i += 256) {
    int4 d = *(const int4*)(vals + e0 + i * 4);
    int x;
    x = d.x - base; if ((unsigned)x < RANGE) atomicAdd(&hist[x], 1);
    x = d.y - base; if ((unsigned)x < RANGE) atomicAdd(&hist[x], 1);
    x = d.z - base; if ((unsigned)x < RANGE) atomicAdd(&hist[x], 1);
    x = d.w - base; if ((unsigned)x < RANGE) atomicAdd(&hist[x], 1);
  }
  __syncthreads();
  for (int j = threadIdx.x; j < RANGE; j += 256)
    part[sl * NPAD + base + j] = hist[j];
}

// ---- A) reduce partials (din & dout) + per-block sums of din ----
__global__ __launch_bounds__(256) void k_scan_a(const int* __restrict__ pdin,
                                                const int* __restrict__ pdout,
                                                int* __restrict__ din,
                                                int* __restrict__ dout,
                                                int* __restrict__ bsum) {
  __shared__ int wsum[4];
  int b = blockIdx.x, t = threadIdx.x;
  int lane = t & 63, w = t >> 6;
  int i0 = b * 1024 + t * 4;
  int4 acc = {0, 0, 0, 0}, od = {0, 0, 0, 0};
  for (int sl = 0; sl < NSLICE; ++sl) {
    int4 a = *(const int4*)(pdin + sl * NPAD + i0);
    int4 o = *(const int4*)(pdout + sl * NPAD + i0);
    acc.x += a.x; acc.y += a.y; acc.z += a.z; acc.w += a.w;
    od.x += o.x; od.y += o.y; od.z += o.z; od.w += o.w;
  }
  *(int4*)(din + i0) = acc;
  *(int4*)(dout + i0) = od;
  int sv = acc.x + acc.y + acc.z + acc.w;
#pragma unroll
  for (int off = 32; off; off >>= 1) sv += __shfl_down(sv, off, 64);
  if (lane == 0) wsum[w] = sv;
  __syncthreads();
  if (t == 0) bsum[b] = wsum[0] + wsum[1] + wsum[2] + wsum[3];
}

// ---- B) exclusive scan of the 49 block sums (one wave) ----
__global__ void k_scan_b(int* __restrict__ bsum, int* __restrict__ row_ptr) {
  int t = threadIdx.x;  // 64 threads
  int v = (t < NSB) ? bsum[t] : 0;
  int orig = v;
#pragma unroll
  for (int off = 1; off < 64; off <<= 1) {
    int u = __shfl_up(v, off, 64);
    if (t >= off) v += u;
  }
  if (t < NSB) bsum[t] = v - orig;   // exclusive block offset
  if (t == 0) row_ptr[NN] = EE;
}

// ---- C) block-level exclusive scan + offset -> row_ptr ----
__global__ __launch_bounds__(256) void k_scan_c(const int* __restrict__ din,
                                                const int* __restrict__ bsum,
                                                int* __restrict__ row_ptr) {
  __shared__ int wsum[4];
  int b = blockIdx.x, t = threadIdx.x;
  int lane = t & 63, w = t >> 6;
  int i0 = b * 1024 + t * 4;
  int4 d = *(const int4*)(din + i0);
  int sth = d.x + d.y + d.z + d.w;
  int v = sth;
#pragma unroll
  for (int off = 1; off < 64; off <<= 1) {
    int u = __shfl_up(v, off, 64);
    if (lane >= off) v += u;
  }
  if (lane == 63) wsum[w] = v;
  __syncthreads();
  int woff = 0;
  for (int j = 0; j < w; ++j) woff += wsum[j];
  int base = bsum[b] + woff + (v - sth);
  if (i0 + 0 <= NN) row_ptr[i0 + 0] = base; base += d.x;
  if (i0 + 1 <= NN) row_ptr[i0 + 1] = base; base += d.y;
  if (i0 + 2 <= NN) row_ptr[i0 + 2] = base; base += d.z;
  if (i0 + 3 <= NN) row_ptr[i0 + 3] = base;
}

// ---- D) in-place: pdin[sl][n] -> row_ptr[n] + sum_{sp<sl} pdin[sp][n] ----
__global__ __launch_bounds__(256) void k_pfx(int* __restrict__ pdin,
                                             const int* __restrict__ row_ptr) {
  int n = blockIdx.x * 256 + threadIdx.x;   // n < NPAD
  int run = row_ptr[n];
#pragma unroll 8
  for (int sl = 0; sl < NSLICE; ++sl) {
    int c = pdin[sl * NPAD + n];
    pdin[sl * NPAD + n] = run;
    run += c;
  }
}

// ---- scatter edge metadata into dst-CSR order: LDS cursors, NO global atomics ----
// 1024 blocks: bits0-5 = slice, bits6+ = partition
// em1 = {src*NJ + ety*128, enorm bits}
__global__ __launch_bounds__(256) void k_scatter(const int* __restrict__ src,
                                                 const int* __restrict__ dst,
                                                 const int* __restrict__ ety,
                                                 const float* __restrict__ enorm,
                                                 const int* __restrict__ pdin,
                                                 int2* __restrict__ em1) {
  __shared__ int cur[RANGE];
  int b = blockIdx.x;
  int sl = b & (NSLICE - 1), r = b >> 6;
  const int base = r * RANGE;
  for (int j = threadIdx.x; j < RANGE; j += 256)
    cur[j] = pdin[sl * NPAD + base + j];
  __syncthreads();
  const int e0 = sl * ESL;
  for (int i = threadIdx.x; i < ESL / 4; i += 256) {
    int4 d = *(const int4*)(dst + e0 + i * 4);
    int vals[4] = {d.x, d.y, d.z, d.w};
#pragma unroll
    for (int j = 0; j < 4; ++j) {
      int dv = vals[j] - base;
      if ((unsigned)dv < RANGE) {
        int e = e0 + i * 4 + j;
        int pos = atomicAdd(&cur[dv], 1);     // LDS fetch-add only
        int sv = src[e];
        int wb = __float_as_int(enorm[e]);
        em1[pos] = make_int2(sv * NJ + ety[e] * 128, wb);
      }
    }
  }
}

// ---- bf16 MFMA GEMM: C[M][ldc] = A[M][128] * B^T (B given as [Ncols][128]) ----
__global__ __launch_bounds__(256) void k_gemm(const unsigned short* __restrict__ A,
                                              const unsigned short* __restrict__ B,
                                              unsigned short* __restrict__ Cbf,
                                              float* __restrict__ Cf,
                                              const float* __restrict__ bias,
                                              int M, int ldc) {
  __shared__ unsigned short As[128 * 136];   // row stride 272 B
  __shared__ unsigned short Bs[128 * 136];
  const int m0 = blockIdx.x * 128, j0 = blockIdx.y * 128;
  const int t = threadIdx.x;
  for (int i = t; i < 2048; i += 256) {
    int r = i >> 4, c = i & 15;
    uint4 va = {0, 0, 0, 0};
    int gr = m0 + r;
    if (gr < M) va = *(const uint4*)(A + (size_t)gr * 128 + c * 8);
    *(uint4*)(&As[r * 136 + c * 8]) = va;
    uint4 vb = *(const uint4*)(B + (size_t)(j0 + r) * 128 + c * 8);
    *(uint4*)(&Bs[r * 136 + c * 8]) = vb;
  }
  __syncthreads();

  const int lane = t & 63, wave = t >> 6;
  const int wr = (wave >> 1) * 64, wc = (wave & 1) * 64;
  const int lr = lane & 15, lk = (lane >> 4) * 8;

  f32x4 acc[4][4];
#pragma unroll
  for (int m = 0; m < 4; ++m)
#pragma unroll
    for (int n = 0; n < 4; ++n) acc[m][n] = (f32x4){0.f, 0.f, 0.f, 0.f};

#pragma unroll
  for (int kt = 0; kt < 4; ++kt) {
    short8 af[4], bfr[4];
#pragma unroll
    for (int m = 0; m < 4; ++m)
      af[m] = *(const short8*)(&As[(wr + m * 16 + lr) * 136 + kt * 32 + lk]);
#pragma unroll
    for (int n = 0; n < 4; ++n)
      bfr[n] = *(const short8*)(&Bs[(wc + n * 16 + lr) * 136 + kt * 32 + lk]);
#pragma unroll
    for (int m = 0; m < 4; ++m)
#pragma unroll
      for (int n = 0; n < 4; ++n)
        acc[m][n] = __builtin_amdgcn_mfma_f32_16x16x32_bf16(af[m], bfr[n], acc[m][n], 0, 0, 0);
  }

#pragma unroll
  for (int m = 0; m < 4; ++m) {
    int rbase = m0 + wr + m * 16 + (lane >> 4) * 4;
#pragma unroll
    for (int i = 0; i < 4; ++i) {
      int row = rbase + i;
      if (row >= M) continue;
      if (Cbf) {
        unsigned short* cr = Cbf + (size_t)row * ldc + j0 + wc;
#pragma unroll
        for (int n = 0; n < 4; ++n) cr[n * 16 + lr] = f2bf(acc[m][n][i]);
      } else {
        float* cr = Cf + (size_t)row * ldc + j0 + wc;
#pragma unroll
        for (int n = 0; n < 4; ++n) cr[n * 16 + lr] = acc[m][n][i] + bias[j0 + wc + n * 16 + lr];
      }
    }
  }
}

#define UNR 8

// ---- layer-1 aggregation: wave per dst node, 8-wide ILP unroll ----
__global__ __launch_bounds__(256) void k_agg1(const unsigned short* __restrict__ xw,
                                              const int2* __restrict__ em1,
                                              const int* __restrict__ row_ptr,
                                              const int* __restrict__ deg_out,
                                              const float* __restrict__ bias1,
                                              unsigned short* __restrict__ hs) {
  int gw = (blockIdx.x * blockDim.x + threadIdx.x) >> 6;
  int lane = threadIdx.x & 63;
  if (gw >= NN) return;
  int beg = row_ptr[gw], end = row_ptr[gw + 1];
  float a0 = 0.f, a1 = 0.f;
  for (int i = beg; i < end; i += UNR) {
    int2 md[UNR];
    unsigned v[UNR];
#pragma unroll
    for (int j = 0; j < UNR; ++j) {
      int idx = i + j;
      idx = idx < end ? idx : end - 1;          // pad: duplicate last edge (MSHR-merged)
      md[j] = em1[idx];
      if (i + j >= end) md[j].y = 0;            // pad weight = 0
    }
#pragma unroll
    for (int j = 0; j < UNR; ++j)
      v[j] = *(const unsigned*)(xw + (size_t)(unsigned)md[j].x + lane * 2);
#pragma unroll
    for (int j = 0; j < UNR; ++j) {
      float w = __int_as_float(md[j].y);
      a0 = fmaf(w, bf2f((unsigned short)(v[j] & 0xffff)), a0);
      a1 = fmaf(w, bf2f((unsigned short)(v[j] >> 16)), a1);
    }
  }
  unsigned vl = *(const unsigned*)(xw + (size_t)gw * NJ + 1024 + lane * 2);
  float ns = rsqrtf(fmaxf((float)deg_out[gw], 1.f));
  float h0 = (a0 + bf2f((unsigned short)(vl & 0xffff)) + bias1[lane * 2]) * ns;
  float h1 = (a1 + bf2f((unsigned short)(vl >> 16)) + bias1[lane * 2 + 1]) * ns;
  unsigned o = (unsigned)f2bf(h0) | ((unsigned)f2bf(h1) << 16);
  *(unsigned*)(hs + (size_t)gw * 128 + lane * 2) = o;
}

// ---- layer-2 aggregation: derives src from em1.x (src = (x>>7)/9) ----
__global__ __launch_bounds__(256) void k_agg2(const unsigned short* __restrict__ hs,
                                              const int2* __restrict__ em1,
                                              const int* __restrict__ row_ptr,
                                              unsigned short* __restrict__ zb) {
  int gw = (blockIdx.x * blockDim.x + threadIdx.x) >> 6;
  int lane = threadIdx.x & 63;
  if (gw >= NN) return;
  int beg = row_ptr[gw], end = row_ptr[gw + 1];
  float a0 = 0.f, a1 = 0.f;
  for (int i = beg; i < end; i += UNR) {
    int2 md[UNR];
    unsigned v[UNR];
#pragma unroll
    for (int j = 0; j < UNR; ++j) {
      int idx = i + j;
      idx = idx < end ? idx : end - 1;
      md[j] = em1[idx];
      if (i + j >= end) md[j].y = 0;
    }
#pragma unroll
    for (int j = 0; j < UNR; ++j) {
      unsigned srcn = (((unsigned)md[j].x) >> 7) / 9u;   // magic-mul division
      v[j] = *(const unsigned*)(hs + ((size_t)srcn << 7) + lane * 2);
    }
#pragma unroll
    for (int j = 0; j < UNR; ++j) {
      float w = __int_as_float(md[j].y);
      a0 = fmaf(w, bf2f((unsigned short)(v[j] & 0xffff)), a0);
      a1 = fmaf(w, bf2f((unsigned short)(v[j] >> 16)), a1);
    }
  }
  float nd = rsqrtf(fmaxf((float)(end - beg), 1.f));
  unsigned o = (unsigned)f2bf(a0 * nd) | ((unsigned)f2bf(a1 * nd) << 16);
  *(unsigned*)(zb + (size_t)gw * 128 + lane * 2) = o;
}

extern "C" void kernel_launch(void* const* d_in, const int* in_sizes, int n_in,
                              void* d_out, int out_size, void* d_ws, size_t ws_size,
                              hipStream_t stream) {
  const float* X = (const float*)d_in[0];
  const int* EI = (const int*)d_in[1];
  const float* enorm = (const float*)d_in[2];
  const int* etype = (const int*)d_in[3];
  const float* wcomp = (const float*)d_in[4];
  const float* bases = (const float*)d_in[5];
  const float* loopw = (const float*)d_in[6];
  const float* bias1 = (const float*)d_in[7];
  const float* W2 = (const float*)d_in[8];
  const float* bias2 = (const float*)d_in[9];
  float* out = (float*)d_out;
  const int* srcA = EI;
  const int* dstA = EI + EE;

  char* p = (char*)d_ws;
  auto alloc = [&](size_t bytes) {
    char* r = p;
    p += (bytes + 255) & ~(size_t)255;
    return r;
  };
  unsigned short* xw  = (unsigned short*)alloc((size_t)NN * NJ * 2);  // 115.2 MB
  unsigned short* Xbf = (unsigned short*)alloc((size_t)NN * 128 * 2);
  unsigned short* hs  = (unsigned short*)alloc((size_t)NN * 128 * 2);
  unsigned short* zb  = (unsigned short*)alloc((size_t)NN * 128 * 2);
  unsigned short* Wt  = (unsigned short*)alloc((size_t)NJ * 128 * 2);
  unsigned short* W2t = (unsigned short*)alloc(128 * 128 * 2);
  int* pdin    = (int*)alloc((size_t)NSLICE * NPAD * 4);
  int* pdout   = (int*)alloc((size_t)NSLICE * NPAD * 4);
  int* din     = (int*)alloc((size_t)NPAD * 4);
  int* dout    = (int*)alloc((size_t)NPAD * 4);
  int* row_ptr = (int*)alloc((size_t)(NPAD + 1) * 4);
  int* bsum    = (int*)alloc((size_t)NSB * 4);
  int2* em1    = (int2*)alloc((size_t)EE * 8);

  hipLaunchKernelGGL(k_prep, dim3(6826), dim3(256), 0, stream,
                     wcomp, bases, loopw, W2, X, Wt, W2t, Xbf);
  hipLaunchKernelGGL(k_hist, dim3(2048), dim3(256), 0, stream, EI, pdin, pdout);
  hipLaunchKernelGGL(k_scan_a, dim3(NSB), dim3(256), 0, stream, pdin, pdout, din, dout, bsum);
  hipLaunchKernelGGL(k_scan_b, dim3(1), dim3(64), 0, stream, bsum, row_ptr);
  hipLaunchKernelGGL(k_scan_c, dim3(NSB), dim3(256), 0, stream, din, bsum, row_ptr);
  hipLaunchKernelGGL(k_pfx, dim3(NPAD / 256), dim3(256), 0, stream, pdin, row_ptr);
  hipLaunchKernelGGL(k_scatter, dim3(1024), dim3(256), 0, stream,
                     srcA, dstA, etype, enorm, pdin, em1);
  hipLaunchKernelGGL(k_gemm, dim3(391, 9), dim3(256), 0, stream,
                     Xbf, Wt, xw, (float*)nullptr, (const float*)nullptr, NN, NJ);
  hipLaunchKernelGGL(k_agg1, dim3(12500), dim3(256), 0, stream,
                     xw, em1, row_ptr, dout, bias1, hs);
  hipLaunchKernelGGL(k_agg2, dim3(12500), dim3(256), 0, stream,
                     hs, em1, row_ptr, zb);
  hipLaunchKernelGGL(k_gemm, dim3(391, 1), dim3(256), 0, stream,
                     zb, W2t, (unsigned short*)nullptr, out, bias2, NN, 128);
}